// Round 3
// baseline (436.889 us; speedup 1.0000x reference)
//
#include <hip/hip_runtime.h>

// SRLoss: loss = mean((inp - avgpool10x10(output))^2) + BCE(output, target)
// output/target: [32,1,1280,1280] f32; inp: [32,1,128,128] f32; out: scalar f32.
//
// R2 post-mortem: VGPR=28 -> compiler sank loads to ~2-deep; occupancy 46%
// (10-wave blocks quantize badly). Still latency-bound at 2.9 TB/s effective.
// R3: 320-thread blocks (5 waves, 6 blocks/CU at VGPR<=64 via launch_bounds
// (320,8)), one band per block = exactly 10 float4-pair iters, explicit
// depth-4 rotating pipeline (8 loads in flight), and BCE refactored to log2
// (single ln2 scale) + fmaxf for the eps-select (inputs >= 0; jax uniform's
// smallest nonzero ~6e-8 >> 1e-20, so fmax == exact-zero replacement).

#define BATCH 32
#define HH 1280
#define WW 1280
#define PH 128
#define PW 128
#define SC 10
#define NT 320                      // threads per block (5 waves)
#define KD 10                       // float4-pair iterations per thread
#define PD 4                        // software-pipeline depth

static constexpr float EPSV = 1e-20f;
static constexpr float LN2  = 0.6931471805599453f;
static constexpr float INV_NB = 1.0f / (float)(BATCH * HH * WW);   // bce mean
static constexpr float INV_NM = 1.0f / (float)(BATCH * PH * PW);   // mse mean

__global__ __launch_bounds__(NT, 8) void srloss_kernel(
    const float* __restrict__ output,
    const float* __restrict__ target,
    const float* __restrict__ inp,
    float* __restrict__ out)
{
    __shared__ float psum[PW];      // pooled column sums for this band
    __shared__ float red[NT / 64];  // cross-wave reduction scratch

    const int t = threadIdx.x;
    const int band = blockIdx.x;    // 0 .. BATCH*PH-1
    const int b = band >> 7;        // band / 128
    const int pr = band & 127;      // band % 128

    if (t < PW) psum[t] = 0.0f;
    __syncthreads();                // before any loads issue (no vmcnt drain)

    const size_t base = ((size_t)b * HH + (size_t)pr * SC) * WW;
    const float4* __restrict__ o4p = (const float4*)(output + base) + t;
    const float4* __restrict__ t4p = (const float4*)(target + base) + t;

    // depth-4 rotating pipeline: 8 outstanding 16B loads per lane
    float4 ob[PD], tb[PD];
    #pragma unroll
    for (int k = 0; k < PD; ++k) {
        ob[k] = o4p[NT * k];
        tb[k] = t4p[NT * k];
    }

    float acc2 = 0.0f;              // sum log2(oc)
    float accd = 0.0f;              // sum t*(log2(om)-log2(oc))
    float s0 = 0.0f, s1 = 0.0f;     // pooled sums: halves of the float4
    #pragma unroll
    for (int k = 0; k < KD; ++k) {
        const float4 o4 = ob[k & (PD - 1)];
        const float4 t4 = tb[k & (PD - 1)];
        if (k + PD < KD) {          // compile-time after unroll
            ob[k & (PD - 1)] = o4p[NT * (k + PD)];
            tb[k & (PD - 1)] = t4p[NT * (k + PD)];
        }
        const float o[4]  = {o4.x, o4.y, o4.z, o4.w};
        const float tg[4] = {t4.x, t4.y, t4.z, t4.w};
        #pragma unroll
        for (int j = 0; j < 4; ++j) {
            const float om = fmaxf(o[j], EPSV);
            const float oc = fmaxf(1.0f - o[j], EPSV);
            const float l1 = __log2f(om);
            const float l2 = __log2f(oc);
            acc2 += l2;
            accd += tg[j] * (l1 - l2);
        }
        s0 += o[0] + o[1];
        s1 += o[2] + o[3];
    }
    const float bce_acc = LN2 * (acc2 + accd);

    // c = t + 320k -> row = k, col0 = 4t for all k (k-invariant mapping)
    const int col0 = 4 * t;
    const int p0 = col0 / SC;
    if ((col0 % SC) == 8) {         // straddle: o[2],o[3] belong to p0+1
        atomicAdd(&psum[p0],     s0);
        atomicAdd(&psum[p0 + 1], s1);
    } else {
        atomicAdd(&psum[p0], s0 + s1);
    }
    __syncthreads();

    // MSE terms: one pooled element per thread for t < 128
    float mse_acc = 0.0f;
    if (t < PW) {
        const float pooled = psum[t] * (1.0f / (float)(SC * SC));
        const float iv = inp[(size_t)band * PW + t];
        const float d = iv - pooled;
        mse_acc = d * d;
    }

    // per-block contribution, pre-normalized
    float contrib = (-INV_NB) * bce_acc + INV_NM * mse_acc;

    #pragma unroll
    for (int off = 32; off > 0; off >>= 1)
        contrib += __shfl_down(contrib, off, 64);
    if ((t & 63) == 0) red[t >> 6] = contrib;
    __syncthreads();
    if (t == 0) {
        float s = 0.0f;
        #pragma unroll
        for (int w = 0; w < NT / 64; ++w) s += red[w];
        atomicAdd(out, s);
    }
}

extern "C" void kernel_launch(void* const* d_in, const int* in_sizes, int n_in,
                              void* d_out, int out_size, void* d_ws, size_t ws_size,
                              hipStream_t stream) {
    const float* output = (const float*)d_in[0];
    const float* target = (const float*)d_in[1];
    const float* inp    = (const float*)d_in[2];
    float* out = (float*)d_out;

    // d_out is poisoned (0xAA) before every timed replay; zero it ourselves.
    hipMemsetAsync(out, 0, sizeof(float), stream);

    srloss_kernel<<<BATCH * PH, NT, 0, stream>>>(output, target, inp, out);
}

// Round 4
// 411.403 us; speedup vs baseline: 1.0619x; 1.0619x over previous
//
#include <hip/hip_runtime.h>

// SRLoss: loss = mean((inp - avgpool10x10(output))^2) + BCE(output, target)
// output/target: [32,1,1280,1280] f32; inp: [32,1,128,128] f32; out: scalar f32.
//
// R3 post-mortem: __launch_bounds__(320,8) capped VGPRs at 64 -> the whole
// rotating pipeline spilled to scratch (WRITE_SIZE 164 MB == 8 float4 x 320thr
// x 4096 blocks). R4: same structure, (320,4) -> 128 VGPR budget, pipeline
// deepened to PD=5 (all 10 float4-pairs/lane in flight, ~75 VGPRs, no spill).
// BCE stays in log2 form (VALUBusy was 11% -> VALU not the bottleneck).

#define BATCH 32
#define HH 1280
#define WW 1280
#define PH 128
#define PW 128
#define SC 10
#define NT 320                      // threads per block (5 waves)
#define KD 10                      // float4-pair iterations per thread
#define PD 5                       // software-pipeline depth (full preload)

static constexpr float EPSV = 1e-20f;
static constexpr float LN2  = 0.6931471805599453f;
static constexpr float INV_NB = 1.0f / (float)(BATCH * HH * WW);   // bce mean
static constexpr float INV_NM = 1.0f / (float)(BATCH * PH * PW);   // mse mean

__global__ __launch_bounds__(NT, 4) void srloss_kernel(
    const float* __restrict__ output,
    const float* __restrict__ target,
    const float* __restrict__ inp,
    float* __restrict__ out)
{
    __shared__ float psum[PW];      // pooled column sums for this band
    __shared__ float red[NT / 64];  // cross-wave reduction scratch

    const int t = threadIdx.x;
    const int band = blockIdx.x;    // 0 .. BATCH*PH-1
    const int b = band >> 7;        // band / 128
    const int pr = band & 127;      // band % 128

    if (t < PW) psum[t] = 0.0f;
    __syncthreads();                // before any loads issue (no vmcnt drain)

    const size_t base = ((size_t)b * HH + (size_t)pr * SC) * WW;
    const float4* __restrict__ o4p = (const float4*)(output + base) + t;
    const float4* __restrict__ t4p = (const float4*)(target + base) + t;

    // depth-5 rotating pipeline: up to 10 outstanding 16B loads per lane
    float4 ob[PD], tb[PD];
    #pragma unroll
    for (int k = 0; k < PD; ++k) {
        ob[k] = o4p[NT * k];
        tb[k] = t4p[NT * k];
    }

    float acc2 = 0.0f;              // sum log2(oc)
    float accd = 0.0f;              // sum t*(log2(om)-log2(oc))
    float s0 = 0.0f, s1 = 0.0f;     // pooled sums: halves of the float4
    #pragma unroll
    for (int k = 0; k < KD; ++k) {
        const float4 o4 = ob[k % PD];
        const float4 t4 = tb[k % PD];
        if (k + PD < KD) {          // compile-time after unroll
            ob[k % PD] = o4p[NT * (k + PD)];
            tb[k % PD] = t4p[NT * (k + PD)];
        }
        const float o[4]  = {o4.x, o4.y, o4.z, o4.w};
        const float tg[4] = {t4.x, t4.y, t4.z, t4.w};
        #pragma unroll
        for (int j = 0; j < 4; ++j) {
            const float om = fmaxf(o[j], EPSV);
            const float oc = fmaxf(1.0f - o[j], EPSV);
            const float l1 = __log2f(om);
            const float l2 = __log2f(oc);
            acc2 += l2;
            accd += tg[j] * (l1 - l2);
        }
        s0 += o[0] + o[1];
        s1 += o[2] + o[3];
    }
    const float bce_acc = LN2 * (acc2 + accd);

    // c = t + 320k -> row = k, col0 = 4t for all k (k-invariant mapping)
    const int col0 = 4 * t;
    const int p0 = col0 / SC;
    if ((col0 % SC) == 8) {         // straddle: o[2],o[3] belong to p0+1
        atomicAdd(&psum[p0],     s0);
        atomicAdd(&psum[p0 + 1], s1);
    } else {
        atomicAdd(&psum[p0], s0 + s1);
    }
    __syncthreads();

    // MSE terms: one pooled element per thread for t < 128
    float mse_acc = 0.0f;
    if (t < PW) {
        const float pooled = psum[t] * (1.0f / (float)(SC * SC));
        const float iv = inp[(size_t)band * PW + t];
        const float d = iv - pooled;
        mse_acc = d * d;
    }

    // per-block contribution, pre-normalized
    float contrib = (-INV_NB) * bce_acc + INV_NM * mse_acc;

    #pragma unroll
    for (int off = 32; off > 0; off >>= 1)
        contrib += __shfl_down(contrib, off, 64);
    if ((t & 63) == 0) red[t >> 6] = contrib;
    __syncthreads();
    if (t == 0) {
        float s = 0.0f;
        #pragma unroll
        for (int w = 0; w < NT / 64; ++w) s += red[w];
        atomicAdd(out, s);
    }
}

extern "C" void kernel_launch(void* const* d_in, const int* in_sizes, int n_in,
                              void* d_out, int out_size, void* d_ws, size_t ws_size,
                              hipStream_t stream) {
    const float* output = (const float*)d_in[0];
    const float* target = (const float*)d_in[1];
    const float* inp    = (const float*)d_in[2];
    float* out = (float*)d_out;

    // d_out is poisoned (0xAA) before every timed replay; zero it ourselves.
    hipMemsetAsync(out, 0, sizeof(float), stream);

    srloss_kernel<<<BATCH * PH, NT, 0, stream>>>(output, target, inp, out);
}